// Round 6
// baseline (5180.302 us; speedup 1.0000x reference)
//
#include <hip/hip_runtime.h>
#include <hip/hip_bf16.h>

// FPS: B=64, N=32768, C=3, S=1024. One block per batch, 1024 threads,
// 32 points/thread.
//
// Round-6: rounds 4/5 failed to get x,y register-resident (VGPR_Count stayed
// 64; the hot loop streamed x,y from L2/scratch every step). A prologue-only
// asm pin doesn't survive regalloc: it blocks remat only AT the pin; the
// values can still be spilled across the 1023-step loop. Fix: pin cx/cy
// INSIDE the step loop — a zero-instruction asm redefinition per step makes
// them loop-carried opaque values; spilling would cost a per-step scratch
// RMW per value, so regalloc must keep them in VGPRs (budget 512/thread at
// 1 block/CU, which our 131 KB LDS already forces).
//
// Exactness (bit-exact trajectory vs XLA-CPU reference, validated round 3):
//   d = fma(dz,dz, fma(dx,dx, dy*dy)), fminf running min,
//   first-occurrence argmax (strict >, ascending index; min index on ties).

#define FPS_N 32768
#define FPS_S 1024
#define FPS_NT 1024
#define FPS_P (FPS_N / FPS_NT)   // 32 points per thread

__global__ __launch_bounds__(FPS_NT, 4) void FPSModel_80753975099708_kernel(
    const float* __restrict__ x,   // [B, N, 3]
    float* __restrict__ out_pts,   // [B, S, 3]
    float* __restrict__ out_idx)   // [B, S] (indices stored as float values)
{
#pragma clang fp contract(off)
    const int b = blockIdx.x;
    const int t = threadIdx.x;
    const float* __restrict__ xb = x + (size_t)b * FPS_N * 3;
    float* __restrict__ op = out_pts + (size_t)b * FPS_S * 3;
    float* __restrict__ oi = out_idx + (size_t)b * FPS_S;

    __shared__ float zsh[FPS_N];                 // z plane: 131072 B
    __shared__ float2 red[2][FPS_NT / 64];       // per-wave (value, idx-bits)

    float cx[FPS_P], cy[FPS_P], mind[FPS_P];

    // Prologue: stage coords. x,y -> registers; z -> LDS.
#pragma unroll
    for (int k = 0; k < FPS_P; ++k) {
        const int i = k * FPS_NT + t;
        const float* __restrict__ p = xb + (size_t)i * 3;
        cx[k] = p[0];
        cy[k] = p[1];
        zsh[i] = p[2];
        mind[k] = __int_as_float(0x7f800000);    // +inf
    }

    int cur = 0;
    if (t == 0) {
        oi[0] = 0.0f;
        op[0] = xb[0];
        op[1] = xb[1];
        op[2] = xb[2];
    }
    __syncthreads();                             // zsh visible to all waves

    for (int s = 1; s < FPS_S; ++s) {
        // Loop-carried opaque redefinition: forces cx/cy to live in VGPRs
        // across the whole step loop (no remat, no profitable spill).
        // Zero instructions emitted.
#pragma unroll
        for (int k = 0; k < FPS_P; ++k) {
            asm volatile("" : "+v"(cx[k]), "+v"(cy[k]));
        }

        // Broadcast read of current farthest point (12 B, L2-resident).
        const float px = xb[(size_t)cur * 3 + 0];
        const float py = xb[(size_t)cur * 3 + 1];
        const float pz = xb[(size_t)cur * 3 + 2];

        float bestv = __int_as_float(0xff800000); // -inf
        int   bestk = 0;                          // i = bestk*1024 + t

#pragma unroll
        for (int k = 0; k < FPS_P; ++k) {
            const float dx = cx[k] - px;
            const float dy = cy[k] - py;
            const float dz = zsh[k * FPS_NT + t] - pz;
            // XLA-CPU contracted form: fma(dz,dz, fma(dx,dx, dy*dy))
            const float dyy = dy * dy;
            const float u   = __builtin_fmaf(dx, dx, dyy);
            const float d   = __builtin_fmaf(dz, dz, u);
            const float m = fminf(mind[k], d);
            mind[k] = m;
            // strict > keeps the smallest k among equal maxima (k ascending)
            if (m > bestv) { bestv = m; bestk = k; }
        }
        int besti = bestk * FPS_NT + t;

        // Wave-level butterfly reduce (64 lanes), tie-break to smaller index.
#pragma unroll
        for (int off = 32; off; off >>= 1) {
            const float ov = __shfl_xor(bestv, off);
            const int   ob = __shfl_xor(besti, off);
            if (ov > bestv || (ov == bestv && ob < besti)) { bestv = ov; besti = ob; }
        }

        const int wave = t >> 6;
        if ((t & 63) == 0) {
            red[s & 1][wave] = make_float2(bestv, __int_as_float(besti));
        }
        __syncthreads();

        // Every thread reduces the 16 wave slots identically (broadcast LDS
        // reads); double-buffered red[] makes next iteration's writes safe.
        float gv = __int_as_float(0xff800000);
        int   gi = 0x7fffffff;
#pragma unroll
        for (int w = 0; w < FPS_NT / 64; ++w) {
            const float2 e = red[s & 1][w];
            const int ei = __float_as_int(e.y);
            if (e.x > gv || (e.x == gv && ei < gi)) { gv = e.x; gi = ei; }
        }
        cur = gi;

        if (t == 0) {
            oi[s] = (float)cur;
            const float* __restrict__ p = xb + (size_t)cur * 3;
            op[(size_t)s * 3 + 0] = p[0];
            op[(size_t)s * 3 + 1] = p[1];
            op[(size_t)s * 3 + 2] = p[2];
        }
    }
}

extern "C" void kernel_launch(void* const* d_in, const int* in_sizes, int n_in,
                              void* d_out, int out_size, void* d_ws, size_t ws_size,
                              hipStream_t stream) {
    const float* x = (const float*)d_in[0];
    const int B = in_sizes[0] / (FPS_N * 3);

    float* out_pts = (float*)d_out;
    float* out_idx = out_pts + (size_t)B * FPS_S * 3;

    hipLaunchKernelGGL(FPSModel_80753975099708_kernel,
                       dim3(B), dim3(FPS_NT), 0, stream,
                       x, out_pts, out_idx);
}